// Round 3
// 493.085 us; speedup vs baseline: 1.1086x; 1.1086x over previous
//
#include <hip/hip_runtime.h>

// Problem constants (reference: B=16, N=2048, D=64, fp32 in/out)
#define Bb 16
#define Nn 2048
#define Dd 64

typedef __attribute__((ext_vector_type(8))) short s16x8;  // 8 bf16 (A/B frag, 16x16x32)
typedef __attribute__((ext_vector_type(4))) short s16x4;  // 4 bf16 (A/B frag, 16x16x16)
typedef __attribute__((ext_vector_type(4))) float fx4;    // MFMA accumulator

__device__ __forceinline__ unsigned short f2bf(float f) {
  union { float f; unsigned u; } v; v.f = f;
  unsigned r = v.u + 0x7FFFu + ((v.u >> 16) & 1u);  // round-to-nearest-even
  return (unsigned short)(r >> 16);
}

// ---- prep 1: K fp32 -> bf16 (row-major [B][N][D]) -------------------------
__global__ void k_cvtK(const float* __restrict__ K, unsigned short* __restrict__ Kb) {
  int i = blockIdx.x * 256 + threadIdx.x;
  float4 f = ((const float4*)K)[i];
  ushort4 o;
  o.x = f2bf(f.x); o.y = f2bf(f.y); o.z = f2bf(f.z); o.w = f2bf(f.w);
  ((ushort4*)Kb)[i] = o;
}

// ---- prep 2: V [B][N][D] fp32 -> VT [B][D][N] bf16 ------------------------
__global__ void k_transV(const float* __restrict__ V, unsigned short* __restrict__ VT) {
  __shared__ float tile[32][33];
  int b = blockIdx.z;
  int j0 = blockIdx.x * 32, d0 = blockIdx.y * 32;
  int tx = threadIdx.x, ty = threadIdx.y;  // block (32,8)
  const float* Vb = V + (size_t)b * Nn * Dd;
  unsigned short* Tb = VT + (size_t)b * Dd * Nn;
  for (int r = ty; r < 32; r += 8)
    tile[r][tx] = Vb[(size_t)(j0 + r) * Dd + d0 + tx];
  __syncthreads();
  for (int r = ty; r < 32; r += 8)
    Tb[(size_t)(d0 + r) * Nn + j0 + tx] = f2bf(tile[tx][r]);
}

// ---- main fused attention -------------------------------------------------
// Split-k x4: block = 256 threads = 4 waves; block owns 16 q rows, wave w owns
// k-range [w*512, (w+1)*512).  Softmax stats (m,l) merged across waves via a
// tiny LDS exchange; partial O tiles merged via a 16 KB LDS buffer.
// Grid = 2048 blocks (vs 512 before) -> 8192 waves -> latency hiding via TLP.
// XCD-chunked block swizzle keeps each XCD's L2 working set at ~2 batches of
// K/V (1 MB).
__global__ __launch_bounds__(256) void k_attn(
    const float* __restrict__ Q, const unsigned short* __restrict__ Kbf,
    const unsigned short* __restrict__ VTbf, const float* __restrict__ scale_p,
    float* __restrict__ ctx, float* att) {
  // XCD-aware bijective swizzle: 2048 blocks, 8 XCDs -> each XCD gets a
  // contiguous run of 256 blocks = 2 batches worth of K/V.
  const int id = blockIdx.x;
  const int swz = ((id & 7) << 8) | (id >> 3);
  const int b = swz >> 7;            // batch
  const int q0 = (swz & 127) << 4;   // q-tile base (16 rows)

  const int tid = threadIdx.x;
  const int wave = tid >> 6, lane = tid & 63;
  const int nl = lane & 15, quad = lane >> 4;
  const int qrow = q0 + nl;
  const float c2 = scale_p[0] * 1.44269504088896341f;  // scale * log2(e)

  __shared__ float sm[4][16];
  __shared__ float sl[4][16];
  __shared__ float ob[4][16][64];  // partial O tiles, 16 KB

  // Q fragment (B operand): B[n=q][k = kt*32 + quad*8 + j], fp32->bf16 inline
  s16x8 qb[2];
  {
    const float* qp = Q + ((size_t)b * Nn + qrow) * Dd + quad * 8;
#pragma unroll
    for (int kt = 0; kt < 2; ++kt) {
      float4 f0 = *(const float4*)(qp + kt * 32);
      float4 f1 = *(const float4*)(qp + kt * 32 + 4);
      s16x8 t;
      t[0] = (short)f2bf(f0.x); t[1] = (short)f2bf(f0.y);
      t[2] = (short)f2bf(f0.z); t[3] = (short)f2bf(f0.w);
      t[4] = (short)f2bf(f1.x); t[5] = (short)f2bf(f1.y);
      t[6] = (short)f2bf(f1.z); t[7] = (short)f2bf(f1.w);
      qb[kt] = t;
    }
  }
  const unsigned short* Kb = Kbf + (size_t)b * Nn * Dd;
  const unsigned short* VTb = VTbf + (size_t)b * Dd * Nn;
  float* attb = att + (size_t)b * Nn * Nn;

  float m = -3.0e38f, l = 0.0f;

  // ---- sweep 1: online max / sum over this wave's 4 k-tiles ---------------
  for (int t = 0; t < 4; ++t) {
    const int k0 = (wave * 4 + t) * 128;
    fx4 s[8];
#pragma unroll
    for (int nt = 0; nt < 8; ++nt) s[nt] = (fx4){0.f, 0.f, 0.f, 0.f};
#pragma unroll
    for (int nt = 0; nt < 8; ++nt) {
      const s16x8* ka =
          (const s16x8*)(Kb + ((size_t)(k0 + nt * 16 + nl)) * Dd + quad * 8);
      s[nt] = __builtin_amdgcn_mfma_f32_16x16x32_bf16(ka[0], qb[0], s[nt], 0, 0, 0);
      s[nt] = __builtin_amdgcn_mfma_f32_16x16x32_bf16(ka[4], qb[1], s[nt], 0, 0, 0);
    }
    float lm = s[0][0];
#pragma unroll
    for (int nt = 0; nt < 8; ++nt)
#pragma unroll
      for (int r = 0; r < 4; ++r) lm = fmaxf(lm, s[nt][r]);
    float mn = fmaxf(m, lm * c2);
    float ls = 0.f;
#pragma unroll
    for (int nt = 0; nt < 8; ++nt)
#pragma unroll
      for (int r = 0; r < 4; ++r) ls += exp2f(fmaf(s[nt][r], c2, -mn));
    l = l * exp2f(m - mn) + ls;
    m = mn;
  }
  // merge the 4 quads (each covered a disjoint k-subset of the same q)
#pragma unroll
  for (int mask = 16; mask <= 32; mask <<= 1) {
    float om = __shfl_xor(m, mask, 64);
    float ol = __shfl_xor(l, mask, 64);
    float mn = fmaxf(m, om);
    l = l * exp2f(m - mn) + ol * exp2f(om - mn);
    m = mn;
  }
  // merge across the 4 waves (disjoint k halves of the same q rows)
  if (lane < 16) { sm[wave][lane] = m; sl[wave][lane] = l; }
  __syncthreads();
  float rinv;
  {
    float M = sm[0][nl], L = sl[0][nl];
#pragma unroll
    for (int j = 1; j < 4; ++j) {
      float mj = sm[j][nl], lj = sl[j][nl];
      float mn = fmaxf(M, mj);
      L = L * exp2f(M - mn) + lj * exp2f(mj - mn);
      M = mn;
    }
    m = M;
    rinv = 1.0f / L;
  }

  // ---- sweep 2: recompute scores, write normalized P, accumulate O=P·V ----
  fx4 o[4];
#pragma unroll
  for (int d = 0; d < 4; ++d) o[d] = (fx4){0.f, 0.f, 0.f, 0.f};

  for (int t = 0; t < 4; ++t) {
    const int k0 = (wave * 4 + t) * 128;
    fx4 s[8];
#pragma unroll
    for (int nt = 0; nt < 8; ++nt) s[nt] = (fx4){0.f, 0.f, 0.f, 0.f};
#pragma unroll
    for (int nt = 0; nt < 8; ++nt) {
      const s16x8* ka =
          (const s16x8*)(Kb + ((size_t)(k0 + nt * 16 + nl)) * Dd + quad * 8);
      s[nt] = __builtin_amdgcn_mfma_f32_16x16x32_bf16(ka[0], qb[0], s[nt], 0, 0, 0);
      s[nt] = __builtin_amdgcn_mfma_f32_16x16x32_bf16(ka[4], qb[1], s[nt], 0, 0, 0);
    }
#pragma unroll
    for (int nt = 0; nt < 8; ++nt) {
      // V loads first (independent of the softmax VALU chain)
      s16x4 vb[4];
#pragma unroll
      for (int ntd = 0; ntd < 4; ++ntd)
        vb[ntd] = *(const s16x4*)(VTb + ((size_t)(ntd * 16 + nl)) * Nn + k0 +
                                  nt * 16 + quad * 4);
      fx4 p;
#pragma unroll
      for (int r = 0; r < 4; ++r)
        p[r] = exp2f(fmaf(s[nt][r], c2, -m)) * rinv;
      // attention row = qrow, cols k0 + nt*16 + quad*4 .. +3 (16B aligned)
      *(fx4*)(attb + (size_t)qrow * Nn + k0 + nt * 16 + quad * 4) = p;
      s16x4 pa;
      pa[0] = (short)f2bf(p[0]); pa[1] = (short)f2bf(p[1]);
      pa[2] = (short)f2bf(p[2]); pa[3] = (short)f2bf(p[3]);
#pragma unroll
      for (int ntd = 0; ntd < 4; ++ntd)
        o[ntd] = __builtin_amdgcn_mfma_f32_16x16x16bf16_1k(pa, vb[ntd], o[ntd], 0, 0, 0);
    }
  }

  // ---- merge partial O across the 4 waves, write ctx ----------------------
#pragma unroll
  for (int ntd = 0; ntd < 4; ++ntd)
#pragma unroll
    for (int r = 0; r < 4; ++r)
      ob[wave][quad * 4 + r][ntd * 16 + nl] = o[ntd][r];
  __syncthreads();
  {
    const int row = tid >> 4;         // 0..15
    const int col = (tid & 15) << 2;  // 0..60 step 4
    fx4 a = *(const fx4*)&ob[0][row][col];
#pragma unroll
    for (int j = 1; j < 4; ++j) {
      fx4 tt = *(const fx4*)&ob[j][row][col];
      a[0] += tt[0]; a[1] += tt[1]; a[2] += tt[2]; a[3] += tt[3];
    }
    *(fx4*)(ctx + ((size_t)b * Nn + q0 + row) * Dd + col) = a;
  }
}

extern "C" void kernel_launch(void* const* d_in, const int* in_sizes, int n_in,
                              void* d_out, int out_size, void* d_ws, size_t ws_size,
                              hipStream_t stream) {
  const float* q = (const float*)d_in[0];
  const float* k = (const float*)d_in[1];
  const float* v = (const float*)d_in[2];
  const float* scale = (const float*)d_in[3];

  float* ctx = (float*)d_out;                       // [16,2048,64]
  float* att = ctx + (size_t)Bb * Nn * Dd;          // [16,2048,2048]

  // workspace: Kbf (4 MB bf16) + VTbf (4 MB bf16); rebuilt every call
  unsigned short* Kbf = (unsigned short*)d_ws;
  unsigned short* VTbf = Kbf + (size_t)Bb * Nn * Dd;

  hipLaunchKernelGGL(k_cvtK, dim3((Bb * Nn * Dd) / (256 * 4)), dim3(256), 0, stream,
                     k, Kbf);
  hipLaunchKernelGGL(k_transV, dim3(Nn / 32, Dd / 32, Bb), dim3(32, 8), 0, stream,
                     v, VTbf);
  hipLaunchKernelGGL(k_attn, dim3(Bb * Nn / 16), dim3(256), 0, stream,
                     q, Kbf, VTbf, scale, ctx, att);
}

// Round 4
// 491.233 us; speedup vs baseline: 1.1128x; 1.0038x over previous
//
#include <hip/hip_runtime.h>

// Problem constants (reference: B=16, N=2048, D=64, fp32 in/out)
#define Bb 16
#define Nn 2048
#define Dd 64

typedef __attribute__((ext_vector_type(8))) short s16x8;  // 8 bf16 (A/B frag, 16x16x32)
typedef __attribute__((ext_vector_type(4))) short s16x4;  // 4 bf16 (A/B frag, 16x16x16)
typedef __attribute__((ext_vector_type(4))) float fx4;    // MFMA accumulator

__device__ __forceinline__ unsigned short f2bf(float f) {
  union { float f; unsigned u; } v; v.f = f;
  unsigned r = v.u + 0x7FFFu + ((v.u >> 16) & 1u);  // round-to-nearest-even
  return (unsigned short)(r >> 16);
}

// ---- prep 1: K fp32 -> bf16 (row-major [B][N][D]) -------------------------
__global__ void k_cvtK(const float* __restrict__ K, unsigned short* __restrict__ Kb) {
  int i = blockIdx.x * 256 + threadIdx.x;
  float4 f = ((const float4*)K)[i];
  ushort4 o;
  o.x = f2bf(f.x); o.y = f2bf(f.y); o.z = f2bf(f.z); o.w = f2bf(f.w);
  ((ushort4*)Kb)[i] = o;
}

// ---- prep 2: V [B][N][D] fp32 -> VT [B][D][N] bf16 ------------------------
__global__ void k_transV(const float* __restrict__ V, unsigned short* __restrict__ VT) {
  __shared__ float tile[32][33];
  int b = blockIdx.z;
  int j0 = blockIdx.x * 32, d0 = blockIdx.y * 32;
  int tx = threadIdx.x, ty = threadIdx.y;  // block (32,8)
  const float* Vb = V + (size_t)b * Nn * Dd;
  unsigned short* Tb = VT + (size_t)b * Dd * Nn;
  for (int r = ty; r < 32; r += 8)
    tile[r][tx] = Vb[(size_t)(j0 + r) * Dd + d0 + tx];
  __syncthreads();
  for (int r = ty; r < 32; r += 8)
    Tb[(size_t)(d0 + r) * Nn + j0 + tx] = f2bf(tile[tx][r]);
}

// ---- main fused attention -------------------------------------------------
// Split-k x4 (4 waves, 16 q rows, wave w owns k in [w*512,(w+1)*512)).
// NEW: att written via nontemporal stores (the 256 MB stream was thrashing the
// 4 MB/XCD L2 and evicting the K/V working set -> L3-latency loads everywhere),
// staged through an XOR-swizzled per-wave LDS tile so each HBM burst is 256 B
// contiguous per row (nt bypasses L2 write-merging, so burst size matters).
__global__ __launch_bounds__(256) void k_attn(
    const float* __restrict__ Q, const unsigned short* __restrict__ Kbf,
    const unsigned short* __restrict__ VTbf, const float* __restrict__ scale_p,
    float* __restrict__ ctx, float* att) {
  // XCD-aware bijective swizzle: 2048 blocks, 8 XCDs -> each XCD gets a
  // contiguous run of 256 blocks = 2 batches worth of K/V (~1 MB in L2).
  const int id = blockIdx.x;
  const int swz = ((id & 7) << 8) | (id >> 3);
  const int b = swz >> 7;            // batch
  const int q0 = (swz & 127) << 4;   // q-tile base (16 rows)

  const int tid = threadIdx.x;
  const int wave = tid >> 6, lane = tid & 63;
  const int nl = lane & 15, quad = lane >> 4;
  const int qrow = q0 + nl;
  const float c2 = scale_p[0] * 1.44269504088896341f;  // scale * log2(e)

  __shared__ float sm[4][16];
  __shared__ float sl[4][16];
  // 16 KB multi-purpose buffer: per-wave P-tile staging during sweep 2
  // (regions disjoint per wave, no barriers needed), then O-merge at the end.
  // Layout: [wave][row 0..15][unit 0..15 XOR (row&7)][4 floats].
  __shared__ float obf[4 * 1024];

  // Q fragment (B operand): B[n=q][k = kt*32 + quad*8 + j], fp32->bf16 inline
  s16x8 qb[2];
  {
    const float* qp = Q + ((size_t)b * Nn + qrow) * Dd + quad * 8;
#pragma unroll
    for (int kt = 0; kt < 2; ++kt) {
      float4 f0 = *(const float4*)(qp + kt * 32);
      float4 f1 = *(const float4*)(qp + kt * 32 + 4);
      s16x8 t;
      t[0] = (short)f2bf(f0.x); t[1] = (short)f2bf(f0.y);
      t[2] = (short)f2bf(f0.z); t[3] = (short)f2bf(f0.w);
      t[4] = (short)f2bf(f1.x); t[5] = (short)f2bf(f1.y);
      t[6] = (short)f2bf(f1.z); t[7] = (short)f2bf(f1.w);
      qb[kt] = t;
    }
  }
  const unsigned short* Kb = Kbf + (size_t)b * Nn * Dd;
  const unsigned short* VTb = VTbf + (size_t)b * Dd * Nn;
  float* attb = att + (size_t)b * Nn * Nn;

  float m = -3.0e38f, l = 0.0f;

  // ---- sweep 1: online max / sum over this wave's 4 k-tiles ---------------
  for (int t = 0; t < 4; ++t) {
    const int k0 = (wave * 4 + t) * 128;
    fx4 s[8];
#pragma unroll
    for (int nt = 0; nt < 8; ++nt) s[nt] = (fx4){0.f, 0.f, 0.f, 0.f};
#pragma unroll
    for (int nt = 0; nt < 8; ++nt) {
      const s16x8* ka =
          (const s16x8*)(Kb + ((size_t)(k0 + nt * 16 + nl)) * Dd + quad * 8);
      s[nt] = __builtin_amdgcn_mfma_f32_16x16x32_bf16(ka[0], qb[0], s[nt], 0, 0, 0);
      s[nt] = __builtin_amdgcn_mfma_f32_16x16x32_bf16(ka[4], qb[1], s[nt], 0, 0, 0);
    }
    // 4 parallel max chains (depth 8) instead of one serial depth-32 chain
    float x0 = s[0][0], x1 = s[0][1], x2 = s[0][2], x3 = s[0][3];
#pragma unroll
    for (int nt = 1; nt < 8; ++nt) {
      x0 = fmaxf(x0, s[nt][0]); x1 = fmaxf(x1, s[nt][1]);
      x2 = fmaxf(x2, s[nt][2]); x3 = fmaxf(x3, s[nt][3]);
    }
    float lm = fmaxf(fmaxf(x0, x1), fmaxf(x2, x3));
    float mn = fmaxf(m, lm * c2);
    // 4 parallel sum chains (depth 8)
    float a0 = 0.f, a1 = 0.f, a2 = 0.f, a3 = 0.f;
#pragma unroll
    for (int nt = 0; nt < 8; ++nt) {
      a0 += exp2f(fmaf(s[nt][0], c2, -mn));
      a1 += exp2f(fmaf(s[nt][1], c2, -mn));
      a2 += exp2f(fmaf(s[nt][2], c2, -mn));
      a3 += exp2f(fmaf(s[nt][3], c2, -mn));
    }
    float ls = (a0 + a1) + (a2 + a3);
    l = l * exp2f(m - mn) + ls;
    m = mn;
  }
  // merge the 4 quads (each covered a disjoint k-subset of the same q)
#pragma unroll
  for (int mask = 16; mask <= 32; mask <<= 1) {
    float om = __shfl_xor(m, mask, 64);
    float ol = __shfl_xor(l, mask, 64);
    float mn = fmaxf(m, om);
    l = l * exp2f(m - mn) + ol * exp2f(om - mn);
    m = mn;
  }
  // merge across the 4 waves (disjoint k quarters of the same q rows)
  if (lane < 16) { sm[wave][lane] = m; sl[wave][lane] = l; }
  __syncthreads();
  float rinv;
  {
    float M = sm[0][nl], L = sl[0][nl];
#pragma unroll
    for (int j = 1; j < 4; ++j) {
      float mj = sm[j][nl], lj = sl[j][nl];
      float mn = fmaxf(M, mj);
      L = L * exp2f(M - mn) + lj * exp2f(mj - mn);
      M = mn;
    }
    m = M;
    rinv = 1.0f / L;
  }

  // ---- sweep 2: recompute scores, stage+flush normalized P, O=P·V ---------
  fx4 o[4];
#pragma unroll
  for (int d = 0; d < 4; ++d) o[d] = (fx4){0.f, 0.f, 0.f, 0.f};

  float* myob = obf + wave * 1024;  // this wave's 16x64 staging tile

  for (int t = 0; t < 4; ++t) {
    const int k0 = (wave * 4 + t) * 128;
    fx4 s[8];
#pragma unroll
    for (int nt = 0; nt < 8; ++nt) s[nt] = (fx4){0.f, 0.f, 0.f, 0.f};
#pragma unroll
    for (int nt = 0; nt < 8; ++nt) {
      const s16x8* ka =
          (const s16x8*)(Kb + ((size_t)(k0 + nt * 16 + nl)) * Dd + quad * 8);
      s[nt] = __builtin_amdgcn_mfma_f32_16x16x32_bf16(ka[0], qb[0], s[nt], 0, 0, 0);
      s[nt] = __builtin_amdgcn_mfma_f32_16x16x32_bf16(ka[4], qb[1], s[nt], 0, 0, 0);
    }
#pragma unroll
    for (int c = 0; c < 2; ++c) {  // two 64-col chunks per 128-col tile
#pragma unroll
      for (int n4 = 0; n4 < 4; ++n4) {
        const int nt = c * 4 + n4;
        // V loads first (independent of the softmax VALU chain)
        s16x4 vb[4];
#pragma unroll
        for (int ntd = 0; ntd < 4; ++ntd)
          vb[ntd] = *(const s16x4*)(VTb + ((size_t)(ntd * 16 + nl)) * Nn + k0 +
                                    nt * 16 + quad * 4);
        fx4 p;
#pragma unroll
        for (int r = 0; r < 4; ++r)
          p[r] = exp2f(fmaf(s[nt][r], c2, -m)) * rinv;
        // stage P: row = q-local (nl), col unit = n4*4+quad, XOR-swizzled
        {
          const int su = (n4 * 4 + quad) ^ (nl & 7);
          *(fx4*)&myob[nl * 64 + su * 4] = p;
        }
        s16x4 pa;
        pa[0] = (short)f2bf(p[0]); pa[1] = (short)f2bf(p[1]);
        pa[2] = (short)f2bf(p[2]); pa[3] = (short)f2bf(p[3]);
#pragma unroll
        for (int ntd = 0; ntd < 4; ++ntd)
          o[ntd] = __builtin_amdgcn_mfma_f32_16x16x16bf16_1k(pa, vb[ntd], o[ntd], 0, 0, 0);
      }
      // drain this wave's ds_writes, then flush the 16x64 chunk as
      // 256 B-contiguous nontemporal bursts (4 rows per instruction)
      asm volatile("s_waitcnt lgkmcnt(0)" ::: "memory");
      {
        const int rl = lane >> 4, un = lane & 15;
#pragma unroll
        for (int rb = 0; rb < 4; ++rb) {
          const int row = rb * 4 + rl;
          const int su = un ^ (row & 7);
          fx4 val = *(const fx4*)&myob[row * 64 + su * 4];
          __builtin_nontemporal_store(
              val, (fx4*)(attb + (size_t)(q0 + row) * Nn + k0 + c * 64 + un * 4));
        }
      }
    }
  }

  // ---- merge partial O across the 4 waves, write ctx ----------------------
  // (same swizzled layout: row = quad*4+r, col = ntd*16+nl)
#pragma unroll
  for (int ntd = 0; ntd < 4; ++ntd)
#pragma unroll
    for (int r = 0; r < 4; ++r) {
      const int row = quad * 4 + r;
      const int unit = ntd * 4 + (nl >> 2);
      const int su = unit ^ (row & 7);
      myob[row * 64 + su * 4 + (nl & 3)] = o[ntd][r];
    }
  __syncthreads();
  {
    const int row = tid >> 4;         // 0..15
    const int un = tid & 15;          // 16B unit
    const int su = un ^ (row & 7);
    fx4 a = *(const fx4*)&obf[row * 64 + su * 4];
#pragma unroll
    for (int j = 1; j < 4; ++j) {
      fx4 tt = *(const fx4*)&obf[j * 1024 + row * 64 + su * 4];
      a[0] += tt[0]; a[1] += tt[1]; a[2] += tt[2]; a[3] += tt[3];
    }
    *(fx4*)(ctx + ((size_t)b * Nn + q0 + row) * Dd + un * 4) = a;
  }
}

extern "C" void kernel_launch(void* const* d_in, const int* in_sizes, int n_in,
                              void* d_out, int out_size, void* d_ws, size_t ws_size,
                              hipStream_t stream) {
  const float* q = (const float*)d_in[0];
  const float* k = (const float*)d_in[1];
  const float* v = (const float*)d_in[2];
  const float* scale = (const float*)d_in[3];

  float* ctx = (float*)d_out;                       // [16,2048,64]
  float* att = ctx + (size_t)Bb * Nn * Dd;          // [16,2048,2048]

  // workspace: Kbf (4 MB bf16) + VTbf (4 MB bf16); rebuilt every call
  unsigned short* Kbf = (unsigned short*)d_ws;
  unsigned short* VTbf = Kbf + (size_t)Bb * Nn * Dd;

  hipLaunchKernelGGL(k_cvtK, dim3((Bb * Nn * Dd) / (256 * 4)), dim3(256), 0, stream,
                     k, Kbf);
  hipLaunchKernelGGL(k_transV, dim3(Nn / 32, Dd / 32, Bb), dim3(32, 8), 0, stream,
                     v, VTbf);
  hipLaunchKernelGGL(k_attn, dim3(Bb * Nn / 16), dim3(256), 0, stream,
                     q, Kbf, VTbf, scale, ctx, att);
}

// Round 5
// 444.100 us; speedup vs baseline: 1.2309x; 1.1061x over previous
//
#include <hip/hip_runtime.h>

// Problem constants (reference: B=16, N=2048, D=64, fp32 in/out)
#define Bb 16
#define Nn 2048
#define Dd 64

typedef __attribute__((ext_vector_type(8))) short s16x8;  // 8 bf16 (A/B frag, 16x16x32)
typedef __attribute__((ext_vector_type(4))) float fx4;    // MFMA accumulator

__device__ __forceinline__ unsigned short f2bf(float f) {
  union { float f; unsigned u; } v; v.f = f;
  unsigned r = v.u + 0x7FFFu + ((v.u >> 16) & 1u);  // round-to-nearest-even
  return (unsigned short)(r >> 16);
}

// ---- prep 1: K fp32 -> bf16 (row-major [B][N][D]) -------------------------
__global__ void k_cvtK(const float* __restrict__ K, unsigned short* __restrict__ Kb) {
  int i = blockIdx.x * 256 + threadIdx.x;
  float4 f = ((const float4*)K)[i];
  ushort4 o;
  o.x = f2bf(f.x); o.y = f2bf(f.y); o.z = f2bf(f.z); o.w = f2bf(f.w);
  ((ushort4*)Kb)[i] = o;
}

// ---- prep 2: V [B][N][D] fp32 -> VT [B][D][N] bf16 ------------------------
__global__ void k_transV(const float* __restrict__ V, unsigned short* __restrict__ VT) {
  __shared__ float tile[32][33];
  int b = blockIdx.z;
  int j0 = blockIdx.x * 32, d0 = blockIdx.y * 32;
  int tx = threadIdx.x, ty = threadIdx.y;  // block (32,8)
  const float* Vb = V + (size_t)b * Nn * Dd;
  unsigned short* Tb = VT + (size_t)b * Dd * Nn;
  for (int r = ty; r < 32; r += 8)
    tile[r][tx] = Vb[(size_t)(j0 + r) * Dd + d0 + tx];
  __syncthreads();
  for (int r = ty; r < 32; r += 8)
    Tb[(size_t)(d0 + r) * Nn + j0 + tx] = f2bf(tile[tx][r]);
}

// ---- main fused attention -------------------------------------------------
// Split-k x4 (4 waves, 16 q rows, wave w owns k in [w*512,(w+1)*512)).
// Sweep-2 restructured to decouple att stores from K/V loads (vmcnt is a
// single in-order counter: a load-wait drains all OLDER stores, so per-nt
// store interleaving serialized every wave on store retirement ~32x/sweep).
// Now: P staged to LDS as bf16 (lgkm domain), PV consumes it as a 16x16x32
// A-fragment (16 MFMA + 16 16B V-loads per tile, half the old counts), and
// the tile's 8 att stores issue as one tail burst -> 4 interleave points.
__global__ __launch_bounds__(256) void k_attn(
    const float* __restrict__ Q, const unsigned short* __restrict__ Kbf,
    const unsigned short* __restrict__ VTbf, const float* __restrict__ scale_p,
    float* __restrict__ ctx, float* __restrict__ att) {
  // XCD-aware bijective swizzle: 2048 blocks, 8 XCDs -> each XCD gets a
  // contiguous run of 256 blocks = 2 batches worth of K/V (~1 MB in L2).
  const int id = blockIdx.x;
  const int swz = ((id & 7) << 8) | (id >> 3);
  const int b = swz >> 7;            // batch
  const int q0 = (swz & 127) << 4;   // q-tile base (16 rows)

  const int tid = threadIdx.x;
  const int wave = tid >> 6, lane = tid & 63;
  const int nl = lane & 15, quad = lane >> 4;
  const int qrow = q0 + nl;
  const float c2 = scale_p[0] * 1.44269504088896341f;  // scale * log2(e)

  __shared__ float sm[4][16];
  __shared__ float sl[4][16];
  // 16 KB multi-purpose: per-wave P staging (bf16, XOR-swizzled) in sweep 2,
  // then O-merge tile at the end. 4 KB per wave, wave-private until merge.
  __shared__ __align__(16) float obf[4 * 1024];
  char* pbw = (char*)obf + wave * 4096;  // this wave's 16 rows x 256 B

  // Q fragment (B operand): B[n=q][k = kt*32 + quad*8 + j], fp32->bf16 inline
  s16x8 qb[2];
  {
    const float* qp = Q + ((size_t)b * Nn + qrow) * Dd + quad * 8;
#pragma unroll
    for (int kt = 0; kt < 2; ++kt) {
      float4 f0 = *(const float4*)(qp + kt * 32);
      float4 f1 = *(const float4*)(qp + kt * 32 + 4);
      s16x8 t;
      t[0] = (short)f2bf(f0.x); t[1] = (short)f2bf(f0.y);
      t[2] = (short)f2bf(f0.z); t[3] = (short)f2bf(f0.w);
      t[4] = (short)f2bf(f1.x); t[5] = (short)f2bf(f1.y);
      t[6] = (short)f2bf(f1.z); t[7] = (short)f2bf(f1.w);
      qb[kt] = t;
    }
  }
  const unsigned short* Kb = Kbf + (size_t)b * Nn * Dd;
  const unsigned short* VTb = VTbf + (size_t)b * Dd * Nn;
  float* attb = att + (size_t)b * Nn * Nn;

  float m = -3.0e38f, l = 0.0f;

  // ---- sweep 1: online max / sum over this wave's 4 k-tiles ---------------
  for (int t = 0; t < 4; ++t) {
    const int k0 = (wave * 4 + t) * 128;
    fx4 s[8];
#pragma unroll
    for (int nt = 0; nt < 8; ++nt) s[nt] = (fx4){0.f, 0.f, 0.f, 0.f};
#pragma unroll
    for (int nt = 0; nt < 8; ++nt) {
      const s16x8* ka =
          (const s16x8*)(Kb + ((size_t)(k0 + nt * 16 + nl)) * Dd + quad * 8);
      s[nt] = __builtin_amdgcn_mfma_f32_16x16x32_bf16(ka[0], qb[0], s[nt], 0, 0, 0);
      s[nt] = __builtin_amdgcn_mfma_f32_16x16x32_bf16(ka[4], qb[1], s[nt], 0, 0, 0);
    }
    // 4 parallel max chains (depth 8) instead of one serial depth-32 chain
    float x0 = s[0][0], x1 = s[0][1], x2 = s[0][2], x3 = s[0][3];
#pragma unroll
    for (int nt = 1; nt < 8; ++nt) {
      x0 = fmaxf(x0, s[nt][0]); x1 = fmaxf(x1, s[nt][1]);
      x2 = fmaxf(x2, s[nt][2]); x3 = fmaxf(x3, s[nt][3]);
    }
    float lm = fmaxf(fmaxf(x0, x1), fmaxf(x2, x3));
    float mn = fmaxf(m, lm * c2);
    // 4 parallel sum chains (depth 8)
    float a0 = 0.f, a1 = 0.f, a2 = 0.f, a3 = 0.f;
#pragma unroll
    for (int nt = 0; nt < 8; ++nt) {
      a0 += exp2f(fmaf(s[nt][0], c2, -mn));
      a1 += exp2f(fmaf(s[nt][1], c2, -mn));
      a2 += exp2f(fmaf(s[nt][2], c2, -mn));
      a3 += exp2f(fmaf(s[nt][3], c2, -mn));
    }
    float ls = (a0 + a1) + (a2 + a3);
    l = l * exp2f(m - mn) + ls;
    m = mn;
  }
  // merge the 4 quads (each covered a disjoint k-subset of the same q)
#pragma unroll
  for (int mask = 16; mask <= 32; mask <<= 1) {
    float om = __shfl_xor(m, mask, 64);
    float ol = __shfl_xor(l, mask, 64);
    float mn = fmaxf(m, om);
    l = l * exp2f(m - mn) + ol * exp2f(om - mn);
    m = mn;
  }
  // merge across the 4 waves (disjoint k quarters of the same q rows)
  if (lane < 16) { sm[wave][lane] = m; sl[wave][lane] = l; }
  __syncthreads();
  float rinv;
  {
    float M = sm[0][nl], L = sl[0][nl];
#pragma unroll
    for (int j = 1; j < 4; ++j) {
      float mj = sm[j][nl], lj = sl[j][nl];
      float mn = fmaxf(M, mj);
      L = L * exp2f(M - mn) + lj * exp2f(mj - mn);
      M = mn;
    }
    m = M;
    rinv = 1.0f / L;
  }

  // ---- sweep 2: QK -> P (regs fp32 + LDS bf16) -> PV -> tail att stores ---
  fx4 o[4];
#pragma unroll
  for (int d = 0; d < 4; ++d) o[d] = (fx4){0.f, 0.f, 0.f, 0.f};

  for (int t = 0; t < 4; ++t) {
    const int k0 = (wave * 4 + t) * 128;
    fx4 s[8];
#pragma unroll
    for (int nt = 0; nt < 8; ++nt) s[nt] = (fx4){0.f, 0.f, 0.f, 0.f};
#pragma unroll
    for (int nt = 0; nt < 8; ++nt) {
      const s16x8* ka =
          (const s16x8*)(Kb + ((size_t)(k0 + nt * 16 + nl)) * Dd + quad * 8);
      s[nt] = __builtin_amdgcn_mfma_f32_16x16x32_bf16(ka[0], qb[0], s[nt], 0, 0, 0);
      s[nt] = __builtin_amdgcn_mfma_f32_16x16x32_bf16(ka[4], qb[1], s[nt], 0, 0, 0);
    }
    // normalize in place (keep fp32 for the att store), stage bf16 P to LDS.
    // s[nt][r] = P[q=nl][k-local = nt*16 + quad*4 + r]
#pragma unroll
    for (int nt = 0; nt < 8; ++nt) {
#pragma unroll
      for (int r = 0; r < 4; ++r)
        s[nt][r] = exp2f(fmaf(s[nt][r], c2, -m)) * rinv;
      unsigned long long pk =
          (unsigned long long)f2bf(s[nt][0]) |
          ((unsigned long long)f2bf(s[nt][1]) << 16) |
          ((unsigned long long)f2bf(s[nt][2]) << 32) |
          ((unsigned long long)f2bf(s[nt][3]) << 48);
      // row nl, true col bytes = nt*32 + quad*8, XOR-swizzled by (nl&7)<<4
      *(unsigned long long*)(pbw + nl * 256 +
                             ((nt * 32 + quad * 8) ^ ((nl & 7) << 4))) = pk;
    }
    // PV: read P back as 16x16x32 A-frag (row=nl, k=kt*32+quad*8+j);
    // V as B-frag (n=d=ntd*16+nl, k contiguous 16B loads). lgkm domain only.
#pragma unroll
    for (int kt = 0; kt < 4; ++kt) {
      s16x8 pa = *(const s16x8*)(pbw + nl * 256 +
                                 ((kt * 64 + quad * 16) ^ ((nl & 7) << 4)));
#pragma unroll
      for (int ntd = 0; ntd < 4; ++ntd) {
        s16x8 vb = *(const s16x8*)(VTb + ((size_t)(ntd * 16 + nl)) * Nn + k0 +
                                   kt * 32 + quad * 8);
        o[ntd] = __builtin_amdgcn_mfma_f32_16x16x32_bf16(pa, vb, o[ntd], 0, 0, 0);
      }
    }
    // tail: this tile's att stores, pinned after the V loads so load-waits
    // never queue behind them (single interleave point per tile).
    __builtin_amdgcn_sched_barrier(0);
#pragma unroll
    for (int nt = 0; nt < 8; ++nt)
      __builtin_nontemporal_store(
          s[nt], (fx4*)(attb + (size_t)qrow * Nn + k0 + nt * 16 + quad * 4));
  }

  // ---- merge partial O across the 4 waves, write ctx ----------------------
  // reuse obf (P staging is dead); XOR-swizzled 16B units, conflict-free.
  {
    float* myob = obf + wave * 1024;
#pragma unroll
    for (int ntd = 0; ntd < 4; ++ntd)
#pragma unroll
      for (int r = 0; r < 4; ++r) {
        const int row = quad * 4 + r;
        const int unit = ntd * 4 + (nl >> 2);
        const int su = unit ^ (row & 7);
        myob[row * 64 + su * 4 + (nl & 3)] = o[ntd][r];
      }
  }
  __syncthreads();
  {
    const int row = tid >> 4;         // 0..15
    const int un = tid & 15;          // 16B unit
    const int su = un ^ (row & 7);
    fx4 a = *(const fx4*)&obf[row * 64 + su * 4];
#pragma unroll
    for (int j = 1; j < 4; ++j) {
      fx4 tt = *(const fx4*)&obf[j * 1024 + row * 64 + su * 4];
      a[0] += tt[0]; a[1] += tt[1]; a[2] += tt[2]; a[3] += tt[3];
    }
    *(fx4*)(ctx + ((size_t)b * Nn + q0 + row) * Dd + un * 4) = a;
  }
}

extern "C" void kernel_launch(void* const* d_in, const int* in_sizes, int n_in,
                              void* d_out, int out_size, void* d_ws, size_t ws_size,
                              hipStream_t stream) {
  const float* q = (const float*)d_in[0];
  const float* k = (const float*)d_in[1];
  const float* v = (const float*)d_in[2];
  const float* scale = (const float*)d_in[3];

  float* ctx = (float*)d_out;                       // [16,2048,64]
  float* att = ctx + (size_t)Bb * Nn * Dd;          // [16,2048,2048]

  // workspace: Kbf (4 MB bf16) + VTbf (4 MB bf16); rebuilt every call
  unsigned short* Kbf = (unsigned short*)d_ws;
  unsigned short* VTbf = Kbf + (size_t)Bb * Nn * Dd;

  hipLaunchKernelGGL(k_cvtK, dim3((Bb * Nn * Dd) / (256 * 4)), dim3(256), 0, stream,
                     k, Kbf);
  hipLaunchKernelGGL(k_transV, dim3(Nn / 32, Dd / 32, Bb), dim3(32, 8), 0, stream,
                     v, VTbf);
  hipLaunchKernelGGL(k_attn, dim3(Bb * Nn / 16), dim3(256), 0, stream,
                     q, Kbf, VTbf, scale, ctx, att);
}